// Round 5
// baseline (1343.033 us; speedup 1.0000x reference)
//
#include <hip/hip_runtime.h>

#define DIM 512
#define BM 128    // rows per workgroup
#define BK 128    // codebook entries per k-tile
#define BD 32     // D-chunk staged in LDS
#define LDP 132   // padded LDS leading dim (floats)
// Flag threshold: reference distances are quantized at ulp(512) = 6.1e-5 by
// the +||z||^2 addition. Any code within 2*ulp of the partial min can win at
// the quantized level; screen error ~1e-7. 2*6.104e-5 + slack:
#define TAU 1.5e-4f

// ||e_k||^2: fp64 accumulation of fp32 (e*e) terms, rounded once to fp32.
// Matches numpy's fp32 pairwise sum to ~1 ulp. Also zeroes the flag counter.
__global__ __launch_bounds__(256) void enorm_kernel(const float* __restrict__ e,
                                                    float* __restrict__ enorm,
                                                    int* __restrict__ count, int K) {
    if (blockIdx.x == 0 && threadIdx.x == 0 && count) *count = 0;
    int w = (blockIdx.x * 256 + threadIdx.x) >> 6;
    int lane = threadIdx.x & 63;
    if (w >= K) return;
    const float4* e4 = (const float4*)(e + (size_t)w * DIM);
    float4 a = e4[lane];
    float4 b = e4[lane + 64];
    // terms are fp32 products (as numpy computes e*e in fp32), summed in fp64
    float t0 = a.x*a.x, t1 = a.y*a.y, t2 = a.z*a.z, t3 = a.w*a.w;
    float t4 = b.x*b.x, t5 = b.y*b.y, t6 = b.z*b.z, t7 = b.w*b.w;
    double s = ((double)t0 + (double)t1) + ((double)t2 + (double)t3)
             + ((double)t4 + (double)t5) + ((double)t6 + (double)t7);
    #pragma unroll
    for (int off = 32; off > 0; off >>= 1) s += __shfl_down(s, off, 64);
    if (lane == 0) enorm[w] = (float)s;
}

// fp32 screen: distance-partial GEMM + argmin + second-best gap + gather.
// WG: 256 threads = 16(tx: codes) x 16(ty: rows); per-thread 8 rows x 8 codes.
__global__ __launch_bounds__(256, 2) void vq_kernel(const float* __restrict__ z,
                                                    const float* __restrict__ e,
                                                    const float* __restrict__ enorm,
                                                    float* __restrict__ out,
                                                    int* __restrict__ count,
                                                    int* __restrict__ list,
                                                    int cap, int N, int K) {
    __shared__ __align__(16) float zs[BD * LDP];   // transposed: zs[dd*LDP+row]
    __shared__ __align__(16) float es[BD * LDP];   // transposed: es[dd*LDP+k]
    __shared__ float redv[BM * 16];
    __shared__ int   redi[BM * 16];
    __shared__ float reds[BM * 16];
    __shared__ int   bestk[BM];

    const int tid = threadIdx.x;
    const int tx = tid & 15;
    const int ty = tid >> 4;
    const int n0 = blockIdx.x * BM;

    float bv[8], sv[8];
    int   bi[8];
    #pragma unroll
    for (int i = 0; i < 8; i++) { bv[i] = 3.4e38f; sv[i] = 3.4e38f; bi[i] = 0; }

    for (int kt = 0; kt < K; kt += BK) {
        float acc[8][8];
        #pragma unroll
        for (int i = 0; i < 8; i++)
            #pragma unroll
            for (int j = 0; j < 8; j++) acc[i][j] = 0.f;

        for (int d0 = 0; d0 < DIM; d0 += BD) {
            #pragma unroll
            for (int l = 0; l < 4; l++) {
                int j = tid + l * 256;
                int row = j >> 3;
                int c = j & 7;
                float4 v = *(const float4*)(z + (size_t)(n0 + row) * DIM + d0 + c * 4);
                zs[(c*4+0)*LDP + row] = v.x;
                zs[(c*4+1)*LDP + row] = v.y;
                zs[(c*4+2)*LDP + row] = v.z;
                zs[(c*4+3)*LDP + row] = v.w;
                float4 w = *(const float4*)(e + (size_t)(kt + row) * DIM + d0 + c * 4);
                es[(c*4+0)*LDP + row] = w.x;
                es[(c*4+1)*LDP + row] = w.y;
                es[(c*4+2)*LDP + row] = w.z;
                es[(c*4+3)*LDP + row] = w.w;
            }
            __syncthreads();
            #pragma unroll 8
            for (int dd = 0; dd < BD; dd++) {
                float4 z0 = *(const float4*)&zs[dd*LDP + ty*8];
                float4 z1 = *(const float4*)&zs[dd*LDP + ty*8+4];
                float4 e0 = *(const float4*)&es[dd*LDP + tx*4];
                float4 e1 = *(const float4*)&es[dd*LDP + tx*4+64];
                float zr[8] = {z0.x, z0.y, z0.z, z0.w, z1.x, z1.y, z1.z, z1.w};
                float ek[8] = {e0.x, e0.y, e0.z, e0.w, e1.x, e1.y, e1.z, e1.w};
                #pragma unroll
                for (int i = 0; i < 8; i++)
                    #pragma unroll
                    for (int jj = 0; jj < 8; jj++)
                        acc[i][jj] = fmaf(zr[i], ek[jj], acc[i][jj]);
            }
            __syncthreads();
        }
        // Partial scores p = ||e||^2 - 2 z.e; running (best, second), first-min.
        #pragma unroll
        for (int jj = 0; jj < 8; jj++) {
            int kk = kt + ((jj < 4) ? (tx*4 + jj) : (64 + tx*4 + (jj - 4)));
            float en = enorm[kk];
            #pragma unroll
            for (int i = 0; i < 8; i++) {
                float s = fmaf(-2.f, acc[i][jj], en);
                if (s < bv[i]) { sv[i] = bv[i]; bv[i] = s; bi[i] = kk; }
                else if (s < sv[i]) sv[i] = s;
            }
        }
    }

    // Cross-tx reduction: lexicographic (val, idx) + global second-best.
    #pragma unroll
    for (int i = 0; i < 8; i++) {
        int row = ty*8 + i;
        redv[row*16 + tx] = bv[i];
        redi[row*16 + tx] = bi[i];
        reds[row*16 + tx] = sv[i];
    }
    __syncthreads();
    if (tid < BM) {
        float v = redv[tid*16];
        int ix = redi[tid*16];
        float s2 = reds[tid*16];
        #pragma unroll
        for (int t = 1; t < 16; t++) {
            float v2 = redv[tid*16 + t];
            int i2 = redi[tid*16 + t];
            float s22 = reds[tid*16 + t];
            if (v2 < v || (v2 == v && i2 < ix)) { s2 = fminf(s22, v); v = v2; ix = i2; }
            else { s2 = fminf(s2, v2); }
        }
        bestk[tid] = ix;
        if (count && (s2 - v < TAU)) {   // quantized argmin may differ -> flag
            int slot = atomicAdd(count, 1);
            if (slot < cap) list[slot] = n0 + tid;
        }
    }
    __syncthreads();

    // Gather: out[row] = e[bestk[row]].
    const float4* e4 = (const float4*)e;
    float4* o4 = (float4*)out;
    for (int j = tid; j < BM * (DIM / 4); j += 256) {
        int row = j >> 7;
        int col = j & 127;
        o4[(size_t)(n0 + row) * (DIM / 4) + col] = e4[(size_t)bestk[row] * (DIM / 4) + col];
    }
}

// Replicated-quantization re-argmin for flagged rows:
//   D_k = fl32( fl32(Z + E_k) - 2 * fl32(dot64) ),  argmin with first-index ties.
// This reproduces numpy's fp32 distance values to ~1e-8 (sgemm noise), and the
// quantized tie structure (ulp(512) = 6.1e-5) exactly.
__global__ __launch_bounds__(256) void fixup_kernel(const float* __restrict__ z,
                                                    const float* __restrict__ e,
                                                    const float* __restrict__ enorm,
                                                    float* __restrict__ out,
                                                    const int* __restrict__ count,
                                                    const int* __restrict__ list,
                                                    int cap, int K) {
    __shared__ double zd[DIM];
    __shared__ float Zrow;
    __shared__ float rv[256];
    __shared__ int   ri[256];
    if (!count) return;
    int cnt = *count;
    if (cnt > cap) cnt = cap;
    for (int li = blockIdx.x; li < cnt; li += gridDim.x) {
        int row = list[li];
        __syncthreads();
        for (int j = threadIdx.x; j < DIM; j += 256) zd[j] = (double)z[(size_t)row*DIM + j];
        __syncthreads();
        if (threadIdx.x == 0) {
            // Z = fp32(sum of fp32(z*z) terms); fp64 accumulation, one rounding.
            // Argmin is invariant to +-k*ulp differences vs numpy's pairwise sum.
            double s = 0.0;
            for (int j = 0; j < DIM; j++) {
                float f = (float)zd[j];
                float t = f * f;
                s += (double)t;
            }
            Zrow = (float)s;
        }
        __syncthreads();
        float Zs = Zrow;
        float best = 3.4e38f;
        int bidx = 0x7fffffff;
        for (int c = threadIdx.x; c < K; c += 256) {   // ascending per thread
            const float4* er4 = (const float4*)(e + (size_t)c * DIM);
            double s = 0.0;
            #pragma unroll 4
            for (int d4 = 0; d4 < DIM/4; d4++) {
                float4 v = er4[d4];
                s = fma(zd[d4*4+0], (double)v.x, s);
                s = fma(zd[d4*4+1], (double)v.y, s);
                s = fma(zd[d4*4+2], (double)v.z, s);
                s = fma(zd[d4*4+3], (double)v.w, s);
            }
            float m = (float)s;              // fl32(dot)
            float T = Zs + enorm[c];         // fl32(Z + E_k)   (quantizes at ulp(512))
            float D = T - 2.0f * m;          // fl32(T - 2m)    (2m exact)
            if (D < best) { best = D; bidx = c; }
        }
        rv[threadIdx.x] = best;
        ri[threadIdx.x] = bidx;
        __syncthreads();
        for (int st = 128; st > 0; st >>= 1) {
            if (threadIdx.x < st) {
                float v2 = rv[threadIdx.x + st];
                int    i2 = ri[threadIdx.x + st];
                if (v2 < rv[threadIdx.x] ||
                    (v2 == rv[threadIdx.x] && i2 < ri[threadIdx.x])) {
                    rv[threadIdx.x] = v2;
                    ri[threadIdx.x] = i2;
                }
            }
            __syncthreads();
        }
        int bk = ri[0];
        const float4* src = (const float4*)(e + (size_t)bk * DIM);
        float4* dst = (float4*)(out + (size_t)row * DIM);
        for (int j = threadIdx.x; j < DIM/4; j += 256) dst[j] = src[j];
    }
}

extern "C" void kernel_launch(void* const* d_in, const int* in_sizes, int n_in,
                              void* d_out, int out_size, void* d_ws, size_t ws_size,
                              hipStream_t stream) {
    const float* z = (const float*)d_in[0];
    const float* e = (const float*)d_in[1];
    float* out = (float*)d_out;
    const int N = in_sizes[0] / DIM;   // 65536
    const int K = in_sizes[1] / DIM;   // 1024

    // ws layout: [0,K) enorm floats | [K] count int | [K+1, ...) flagged row list
    float* enorm = (float*)d_ws;
    long ws_elems = (long)(ws_size / 4);
    bool have_list = ws_elems >= K + 2;
    int* count = have_list ? ((int*)d_ws + K) : nullptr;
    int* list  = have_list ? ((int*)d_ws + K + 1) : nullptr;
    long cap_l = have_list ? (ws_elems - K - 1) : 0;
    int cap = cap_l > N ? N : (int)cap_l;

    enorm_kernel<<<dim3((K + 3) / 4), dim3(256), 0, stream>>>(e, enorm, count, K);
    vq_kernel<<<dim3(N / BM), dim3(256), 0, stream>>>(z, e, enorm, out, count, list, cap, N, K);
    fixup_kernel<<<dim3(512), dim3(256), 0, stream>>>(z, e, enorm, out, count, list, cap, K);
}